// Round 9
// baseline (486.165 us; speedup 1.0000x reference)
//
#include <hip/hip_runtime.h>
#include <hip/hip_bf16.h>

typedef __attribute__((ext_vector_type(8))) short bf16x8;
typedef __attribute__((ext_vector_type(4))) float f32x4;

// ---------------- numerics (match jnp reference) ----------------

__device__ __forceinline__ float silu_mul_f(float a, float b) {
  float s = 1.0f / (1.0f + expf(-a));
  return (a * s) * b;
}

__device__ __forceinline__ int flog2(float a) {
  return (int)((__float_as_uint(a) >> 23) & 255u) - 127;
}
__device__ __forceinline__ float exp2i(int e) {
  return __uint_as_float((unsigned)(e + 127) << 23);
}

__device__ __forceinline__ float round_e4m3_f(float a) {  // a >= 0
  if (!(a > 0.0f)) return 0.0f;
  int e = flog2(a);
  e = e < -6 ? -6 : (e > 8 ? 8 : e);
  float q = rintf(a * exp2i(3 - e)) * exp2i(e - 3);
  return fminf(q, 448.0f);
}

__device__ __forceinline__ float round_e2m1_f(float x) {
  float a = fminf(fabsf(x), 6.0f);
  if (!(a > 0.0f)) return 0.0f;
  int e = flog2(a);
  e = e < 0 ? 0 : (e > 2 ? 2 : e);
  float q = rintf(a * exp2i(1 - e)) * exp2i(e - 1);
  q = fminf(q, 6.0f);
  return (x < 0.0f) ? -q : q;
}

__global__ void init_scal_kernel(float* scal) {
  if (threadIdx.x < 2) scal[threadIdx.x] = 0.0f;
}

// ---------------- pass 1: region-split amax, x2 unrolled (R8 unchanged) ----------------

__device__ __forceinline__ float act_unit_max(const float* __restrict__ x, long u,
                                              int hidden, long hqm, int hqLog) {
  long row = u >> hqLog, c = u & hqm;
  const float* xr = x + ((row * (long)hidden) << 1);
  float4 v1 = ((const float4*)xr)[c];
  float4 v2 = ((const float4*)(xr + hidden))[c];
  float m = fmaxf(fabsf(silu_mul_f(v1.x, v2.x)), fabsf(silu_mul_f(v1.y, v2.y)));
  m = fmaxf(m, fmaxf(fabsf(silu_mul_f(v1.z, v2.z)), fabsf(silu_mul_f(v1.w, v2.w))));
  return m;
}

__global__ void amax2_kernel(const float* __restrict__ x, const float* __restrict__ w,
                             float* __restrict__ scal, long actU, long wU,
                             int hidden, int hqLog, int AB) {
  const long hqm = (1L << hqLog) - 1;
  float m = 0.0f;
  int which;
  if ((int)blockIdx.x < AB) {
    which = 0;
    const long stride = (long)AB * blockDim.x;
    long u = (long)blockIdx.x * blockDim.x + threadIdx.x;
    for (; u + stride < actU; u += 2 * stride) {
      float m0 = act_unit_max(x, u, hidden, hqm, hqLog);
      float m1 = act_unit_max(x, u + stride, hidden, hqm, hqLog);
      m = fmaxf(m, fmaxf(m0, m1));
    }
    if (u < actU) m = fmaxf(m, act_unit_max(x, u, hidden, hqm, hqLog));
  } else {
    which = 1;
    const long stride = (long)(gridDim.x - AB) * blockDim.x;
    long u = (long)((int)blockIdx.x - AB) * blockDim.x + threadIdx.x;
    for (; u + stride < wU; u += 2 * stride) {
      float4 v1 = ((const float4*)w)[u];
      float4 v2 = ((const float4*)w)[u + stride];
      float m0 = fmaxf(fmaxf(fabsf(v1.x), fabsf(v1.y)), fmaxf(fabsf(v1.z), fabsf(v1.w)));
      float m1 = fmaxf(fmaxf(fabsf(v2.x), fabsf(v2.y)), fmaxf(fabsf(v2.z), fabsf(v2.w)));
      m = fmaxf(m, fmaxf(m0, m1));
    }
    if (u < wU) {
      float4 v = ((const float4*)w)[u];
      m = fmaxf(m, fmaxf(fmaxf(fabsf(v.x), fabsf(v.y)), fmaxf(fabsf(v.z), fabsf(v.w))));
    }
  }
#pragma unroll
  for (int off = 32; off > 0; off >>= 1) m = fmaxf(m, __shfl_xor(m, off));
  __shared__ float sm[4];
  if ((threadIdx.x & 63) == 0) sm[threadIdx.x >> 6] = m;
  __syncthreads();
  if (threadIdx.x == 0) {
    float mm = fmaxf(fmaxf(sm[0], sm[1]), fmaxf(sm[2], sm[3]));
    atomicMax((unsigned int*)(scal + which), __float_as_uint(mm));
  }
}

// ---------------- pass 2: region-split quad-cooperative quant (R8 unchanged) ----------------

__device__ __forceinline__ void quant_unit(float y0, float y1, float y2, float y3,
                                           float gs, unsigned short* dst) {
  float lm = fmaxf(fmaxf(fabsf(y0), fabsf(y1)), fmaxf(fabsf(y2), fabsf(y3)));
  lm = fmaxf(lm, __shfl_xor(lm, 1));
  lm = fmaxf(lm, __shfl_xor(lm, 2));           // 16-elem block amax across the quad
  float bs = round_e4m3_f(lm / 6.0f * gs);
  float r = gs / (bs > 0.0f ? bs : 1.0f);
  ushort4 o;
  o.x = (unsigned short)(__float_as_uint(round_e2m1_f(y0 * r) * bs) >> 16);
  o.y = (unsigned short)(__float_as_uint(round_e2m1_f(y1 * r) * bs) >> 16);
  o.z = (unsigned short)(__float_as_uint(round_e2m1_f(y2 * r) * bs) >> 16);
  o.w = (unsigned short)(__float_as_uint(round_e2m1_f(y3 * r) * bs) >> 16);
  *(ushort4*)dst = o;                          // q*bs <= 6 sig bits -> exact bf16
}

__global__ void quant2_kernel(const float* __restrict__ x, const float* __restrict__ w,
                              __hip_bfloat16* __restrict__ A, __hip_bfloat16* __restrict__ B,
                              const float* __restrict__ scal, long actU, long wU,
                              int hidden, int hqLog, int AB) {
  const long hqm = (1L << hqLog) - 1;
  if ((int)blockIdx.x < AB) {
    const float gs = 2688.0f / scal[0];
    const long stride = (long)AB * blockDim.x;
    long u = (long)blockIdx.x * blockDim.x + threadIdx.x;
    for (; u + stride < actU; u += 2 * stride) {
      long ua = u, ub = u + stride;
      long ra = ua >> hqLog, ca = ua & hqm;
      long rb = ub >> hqLog, cb = ub & hqm;
      const float* xa = x + ((ra * (long)hidden) << 1) + (ca << 2);
      const float* xb = x + ((rb * (long)hidden) << 1) + (cb << 2);
      float4 a1 = *(const float4*)xa;
      float4 a2 = *(const float4*)(xa + hidden);
      float4 b1 = *(const float4*)xb;
      float4 b2 = *(const float4*)(xb + hidden);
      quant_unit(silu_mul_f(a1.x, a2.x), silu_mul_f(a1.y, a2.y),
                 silu_mul_f(a1.z, a2.z), silu_mul_f(a1.w, a2.w),
                 gs, (unsigned short*)A + (ua << 2));
      quant_unit(silu_mul_f(b1.x, b2.x), silu_mul_f(b1.y, b2.y),
                 silu_mul_f(b1.z, b2.z), silu_mul_f(b1.w, b2.w),
                 gs, (unsigned short*)A + (ub << 2));
    }
    if (u < actU) {
      long c = u & hqm;
      const float* xa = x + (((u >> hqLog) * (long)hidden) << 1) + (c << 2);
      float4 v1 = *(const float4*)xa;
      float4 v2 = *(const float4*)(xa + hidden);
      quant_unit(silu_mul_f(v1.x, v2.x), silu_mul_f(v1.y, v2.y),
                 silu_mul_f(v1.z, v2.z), silu_mul_f(v1.w, v2.w),
                 gs, (unsigned short*)A + (u << 2));
    }
  } else {
    const float gs = 2688.0f / scal[1];
    const long stride = (long)(gridDim.x - AB) * blockDim.x;
    long u = (long)((int)blockIdx.x - AB) * blockDim.x + threadIdx.x;
    for (; u + stride < wU; u += 2 * stride) {
      float4 v1 = ((const float4*)w)[u];
      float4 v2 = ((const float4*)w)[u + stride];
      quant_unit(v1.x, v1.y, v1.z, v1.w, gs, (unsigned short*)B + (u << 2));
      quant_unit(v2.x, v2.y, v2.z, v2.w, gs, (unsigned short*)B + ((u + stride) << 2));
    }
    if (u < wU) {
      float4 v = ((const float4*)w)[u];
      quant_unit(v.x, v.y, v.z, v.w, gs, (unsigned short*)B + (u << 2));
    }
  }
}

// ---------------- pass 3: 128x128 bf16 GEMM, 16x16x32, never-drain, 2 blocks/CU ------
// 8 waves (2M x 4N), wave output 64x32 -> acc 32 VGPR; LDS 64 KiB (A/B x 2 parity x
// 2 khalf regions of 8 KB) -> 2 blocks/CU, 4 waves/SIMD (launch_bounds(512,4)).
// Same proven 0-conflict geometry as R5: 64B rows, phys slot = slot ^ ((row>>1)&3),
// involution on staging source + read (rule #21). Never-drain ledger:
//   staging: P1 A(kh0,T+1), P2 B(kh0,T+1), P3 A(kh1,T+1), P4 B(kh1,T+1) [1 gload each]
//   VMW(2) at P2 forces T.kh1 (older 2) done, leaves T+1.kh0 in flight;
//   VMW(2) at P4 forces T+1.kh0 done, leaves T+1.kh1 in flight. Never 0 in loop.
//   lgkm: reads 1 phase ahead; WAITL(2)/(4) alternating forces exactly the older set.
// WAR safety: region (P,khX) overwritten at T+1.P1/P3, one full barrier after every
// wave's reads of it are lgkm-forced complete (audited per-phase).

__device__ __forceinline__ void gload_lds16(const void* g, void* l) {
  __builtin_amdgcn_global_load_lds(
      (const __attribute__((address_space(1))) void*)(uintptr_t)g,
      (__attribute__((address_space(3))) void*)(uintptr_t)l, 16, 0, 0);
}

template <unsigned IMM>
__device__ __forceinline__ bf16x8 lds_read16o(unsigned addr) {
  bf16x8 r;
  asm volatile("ds_read_b128 %0, %1 offset:%c2" : "=&v"(r) : "v"(addr), "i"(IMM));
  return r;
}

__device__ __forceinline__ f32x4 mfma_(bf16x8 a, bf16x8 b, f32x4 c) {
  return __builtin_amdgcn_mfma_f32_16x16x32_bf16(a, b, c, 0, 0, 0);
}

#define SP1 __builtin_amdgcn_s_setprio(1)
#define SP0 __builtin_amdgcn_s_setprio(0)
#define SCHEDB __builtin_amdgcn_sched_barrier(0)
#define WAITL(n) do { asm volatile("s_waitcnt lgkmcnt(" #n ")" ::: "memory"); SCHEDB; } while (0)
#define VMW2 do { asm volatile("s_waitcnt vmcnt(2)" ::: "memory"); } while (0)

// one gload: region (mat, parity PP, khalf HH); source col = KSB + HH*64 bytes
#define STAGEA(PP, HH, KSB) \
    gload_lds16(pa + (KSB) + (HH) * 64, ldsStA + (PP) * 16384 + (HH) * 8192)
#define STAGEB(PP, HH, KSB) \
    gload_lds16(pb + (KSB) + (HH) * 64, ldsStB + (PP) * 16384 + (HH) * 8192)

// A m-pair frags (MB, MB+1), B n-pair frags
#define RD2A(DST, PP, HH, MB) do {                                              \
    DST[0] = lds_read16o<(PP)*16384u + (HH)*8192u + ((MB)+0)*1024u>(vA);        \
    DST[1] = lds_read16o<(PP)*16384u + (HH)*8192u + ((MB)+1)*1024u>(vA); } while (0)

#define RD2B(DST, PP, HH) do {                                                  \
    DST[0] = lds_read16o<(PP)*16384u + (HH)*8192u + 0u>(vB);                    \
    DST[1] = lds_read16o<(PP)*16384u + (HH)*8192u + 1024u>(vB); } while (0)

#define MFMA4(AF, BF, MB) do {                                                  \
    acc[(MB)+0][0] = mfma_(AF[0], BF[0], acc[(MB)+0][0]);                       \
    acc[(MB)+1][0] = mfma_(AF[1], BF[0], acc[(MB)+1][0]);                       \
    acc[(MB)+0][1] = mfma_(AF[0], BF[1], acc[(MB)+0][1]);                       \
    acc[(MB)+1][1] = mfma_(AF[1], BF[1], acc[(MB)+1][1]); } while (0)

// one K-tile (BK=64): consume parity P; stage tile T+1 (parity P^1) at col byte off KSB
#define TILE(P, KSB) do {                                                       \
    /* P1: kh0 x m01 */                                                         \
    STAGEA((P)^1, 0, KSB);                                                      \
    RD2A(aN, P, 0, 2);                   /* a23 <- (P,kh0) */                   \
    SP1; WAITL(2); MFMA4(aC, bC, 0); SP0;                                       \
    /* P2: kh0 x m23 */                                                         \
    STAGEB((P)^1, 0, KSB);                                                      \
    VMW2; __builtin_amdgcn_s_barrier(); SCHEDB;                                 \
    RD2A(aC, P, 1, 0); RD2B(bN, P, 1);   /* a01',b1 <- (P,kh1) */               \
    SP1; WAITL(4); MFMA4(aN, bC, 2); SP0;                                       \
    /* P3: kh1 x m01 */                                                         \
    STAGEA((P)^1, 1, KSB);                                                      \
    RD2A(aN, P, 1, 2);                   /* a23' <- (P,kh1) */                  \
    SP1; WAITL(2); MFMA4(aC, bN, 0); SP0;                                       \
    /* P4: kh1 x m23 */                                                         \
    STAGEB((P)^1, 1, KSB);                                                      \
    VMW2; __builtin_amdgcn_s_barrier(); SCHEDB;                                 \
    RD2A(aC, (P)^1, 0, 0); RD2B(bC, (P)^1, 0);  /* next tile a01,b0 */          \
    SP1; WAITL(4); MFMA4(aN, bN, 2); SP0;                                       \
  } while (0)

__global__ __launch_bounds__(512, 4) void gemm_bt_kernel(
    const __hip_bfloat16* __restrict__ A, const __hip_bfloat16* __restrict__ B,
    float* __restrict__ C, const float* __restrict__ scal, int M, int N, int K) {
  // LDS 64 KiB: A regions [par][kh] 8 KB each @ par*16384+kh*8192; B same @ +32768
  __shared__ __align__(16) char lds[65536];

  // XCD-banded wg map: each XCD gets an 8-row bm band, bn-major.
  const int nbm = M >> 7, nbn = N >> 7;
  int wg = blockIdx.x, bm, bn;
  if ((nbm & 7) == 0) {
    int band = nbm >> 3;
    int xcd = wg & 7, c = wg >> 3;
    bm = xcd * band + (c % band);
    bn = c / band;
  } else {
    bm = wg / nbn; bn = wg % nbn;
  }
  const int brow = bm << 7, bcol = bn << 7;

  const int tid = threadIdx.x;
  const int lane = tid & 63;
  const int wave = tid >> 6;
  const int wm = wave >> 2, wn = wave & 3;   // 2M x 4N; wave output 64x32

  // staging: one 16B chunk per (mat,khalf): row = tid>>2 (0..127), phys slot = tid&3,
  // logical kchunk = phys ^ ((row>>1)&3) = (tid&3)^((tid>>3)&3)
  const int srow = tid >> 2;
  const int slc = (tid & 3) ^ ((tid >> 3) & 3);
  const char* pa = (const char*)(A + (size_t)(brow + srow) * K + slc * 8);
  const char* pb = (const char*)(B + (size_t)(bcol + srow) * K + slc * 8);
  char* ldsStA = lds + tid * 16;
  char* ldsStB = lds + 32768 + tid * 16;

  // fragment reads: row R = wbase + 16m + (lane&15); kchunk = lane>>4;
  // phys = kchunk ^ ((R>>1)&3) = kchunk ^ ((lane>>1)&3)   [measured 0 conflicts, R5/R8]
  const unsigned ldsBase = (unsigned)(uintptr_t)lds;
  const unsigned xoff = (unsigned)((lane & 15) * 64) +
                        ((((unsigned)(lane >> 4)) ^ (((unsigned)lane >> 1) & 3u)) << 4);
  const unsigned vA = ldsBase + (unsigned)(wm * 4096) + xoff;
  const unsigned vB = ldsBase + 32768u + (unsigned)(wn * 2048) + xoff;

  f32x4 acc[4][2] = {};
  bf16x8 aC[2], aN[2], bC[2], bN[2];

  // prologue: stage tile 0 (parity 0) fully, publish, issue a01/b0 reads
  STAGEA(0, 0, 0); STAGEB(0, 0, 0); STAGEA(0, 1, 0); STAGEB(0, 1, 0);
  asm volatile("s_waitcnt vmcnt(0)" ::: "memory");
  __syncthreads();
  RD2A(aC, 0, 0, 0); RD2B(bC, 0, 0); SCHEDB;

  const int nt = K >> 6;  // K-tiles (BK=64)
  for (int it = 0; it < (nt >> 1); ++it) {
    int t0 = it << 1;
    int ks0 = (t0 + 1) * 128;                       // stage tile t0+1
    int ks1 = (t0 + 2 == nt) ? 0 : (t0 + 2) * 128;  // stage tile t0+2 (dead at tail)
    TILE(0, ks0);
    TILE(1, ks1);
  }
  asm volatile("s_waitcnt lgkmcnt(0)" ::: "memory");
  asm volatile("s_waitcnt vmcnt(0)" ::: "memory");

  float gy = 2688.0f / scal[0];
  float gw = 2688.0f / scal[1];
  float alpha = 1.0f / (gy * gw);

  // C/D layout: col = lane&15, row = (lane>>4)*4 + reg
#pragma unroll
  for (int m = 0; m < 4; ++m) {
    int rbase = brow + wm * 64 + m * 16 + ((lane >> 4) << 2);
#pragma unroll
    for (int n = 0; n < 2; ++n) {
      int col = bcol + wn * 32 + n * 16 + (lane & 15);
#pragma unroll
      for (int rg = 0; rg < 4; ++rg) {
        C[(size_t)(rbase + rg) * N + col] = acc[m][n][rg] * alpha;
      }
    }
  }
}

// ---------------- launcher ----------------

extern "C" void kernel_launch(void* const* d_in, const int* in_sizes, int n_in,
                              void* d_out, int out_size, void* d_ws, size_t ws_size,
                              hipStream_t stream) {
  const float* x = (const float*)d_in[0];
  const float* w = (const float*)d_in[1];
  float* out = (float*)d_out;

  int hidden = 1;
  while ((long long)hidden * hidden < (long long)in_sizes[1]) hidden <<= 1;
  int tokens = in_sizes[0] / (2 * hidden);

  char* ws = (char*)d_ws;
  __hip_bfloat16* Aq = (__hip_bfloat16*)ws;
  __hip_bfloat16* Bq = (__hip_bfloat16*)(ws + (size_t)tokens * hidden * 2);
  float* scal = (float*)(ws + (size_t)tokens * hidden * 2 + (size_t)hidden * hidden * 2);

  long actU = (long)tokens * hidden / 4;   // float4 units of y
  long wU = (long)hidden * hidden / 4;     // float4 units of w
  int hqLog = __builtin_ctz((unsigned)(hidden >> 2));
  int nBlk = 2048;
  int AB = (int)(((long)nBlk * actU) / (actU + wU));  // act/w block split (~2:1)
  AB &= ~3;
  if (AB < 1) AB = 1;
  if (AB > nBlk - 1) AB = nBlk - 1;

  init_scal_kernel<<<1, 64, 0, stream>>>(scal);
  amax2_kernel<<<nBlk, 256, 0, stream>>>(x, w, scal, actU, wU, hidden, hqLog, AB);
  quant2_kernel<<<nBlk, 256, 0, stream>>>(x, w, Aq, Bq, scal, actU, wU, hidden, hqLog, AB);

  int grid = (tokens >> 7) * (hidden >> 7);  // 128x128 tiles
  gemm_bt_kernel<<<grid, 512, 0, stream>>>(Aq, Bq, out, scal, tokens, hidden, hidden);
}

// Round 10
// 378.439 us; speedup vs baseline: 1.2847x; 1.2847x over previous
//
#include <hip/hip_runtime.h>
#include <hip/hip_bf16.h>

typedef __attribute__((ext_vector_type(8))) short bf16x8;
typedef __attribute__((ext_vector_type(4))) float f32x4;

// ---------------- numerics (match jnp reference) ----------------

__device__ __forceinline__ float silu_mul_f(float a, float b) {
  float s = 1.0f / (1.0f + expf(-a));
  return (a * s) * b;
}

__device__ __forceinline__ int flog2(float a) {
  return (int)((__float_as_uint(a) >> 23) & 255u) - 127;
}
__device__ __forceinline__ float exp2i(int e) {
  return __uint_as_float((unsigned)(e + 127) << 23);
}

__device__ __forceinline__ float round_e4m3_f(float a) {  // a >= 0
  if (!(a > 0.0f)) return 0.0f;
  int e = flog2(a);
  e = e < -6 ? -6 : (e > 8 ? 8 : e);
  float q = rintf(a * exp2i(3 - e)) * exp2i(e - 3);
  return fminf(q, 448.0f);
}

__device__ __forceinline__ float round_e2m1_f(float x) {
  float a = fminf(fabsf(x), 6.0f);
  if (!(a > 0.0f)) return 0.0f;
  int e = flog2(a);
  e = e < 0 ? 0 : (e > 2 ? 2 : e);
  float q = rintf(a * exp2i(1 - e)) * exp2i(e - 1);
  q = fminf(q, 6.0f);
  return (x < 0.0f) ? -q : q;
}

__global__ void init_scal_kernel(float* scal) {
  if (threadIdx.x < 2) scal[threadIdx.x] = 0.0f;
}

// ---------------- pass 1: region-split amax, x2 unrolled ----------------

__device__ __forceinline__ float act_unit_max(const float* __restrict__ x, long u,
                                              int hidden, long hqm, int hqLog) {
  long row = u >> hqLog, c = u & hqm;
  const float* xr = x + ((row * (long)hidden) << 1);
  float4 v1 = ((const float4*)xr)[c];
  float4 v2 = ((const float4*)(xr + hidden))[c];
  float m = fmaxf(fabsf(silu_mul_f(v1.x, v2.x)), fabsf(silu_mul_f(v1.y, v2.y)));
  m = fmaxf(m, fmaxf(fabsf(silu_mul_f(v1.z, v2.z)), fabsf(silu_mul_f(v1.w, v2.w))));
  return m;
}

__global__ void amax2_kernel(const float* __restrict__ x, const float* __restrict__ w,
                             float* __restrict__ scal, long actU, long wU,
                             int hidden, int hqLog, int AB) {
  const long hqm = (1L << hqLog) - 1;
  float m = 0.0f;
  int which;
  if ((int)blockIdx.x < AB) {
    which = 0;
    const long stride = (long)AB * blockDim.x;
    long u = (long)blockIdx.x * blockDim.x + threadIdx.x;
    for (; u + stride < actU; u += 2 * stride) {
      float m0 = act_unit_max(x, u, hidden, hqm, hqLog);
      float m1 = act_unit_max(x, u + stride, hidden, hqm, hqLog);
      m = fmaxf(m, fmaxf(m0, m1));
    }
    if (u < actU) m = fmaxf(m, act_unit_max(x, u, hidden, hqm, hqLog));
  } else {
    which = 1;
    const long stride = (long)(gridDim.x - AB) * blockDim.x;
    long u = (long)((int)blockIdx.x - AB) * blockDim.x + threadIdx.x;
    for (; u + stride < wU; u += 2 * stride) {
      float4 v1 = ((const float4*)w)[u];
      float4 v2 = ((const float4*)w)[u + stride];
      float m0 = fmaxf(fmaxf(fabsf(v1.x), fabsf(v1.y)), fmaxf(fabsf(v1.z), fabsf(v1.w)));
      float m1 = fmaxf(fmaxf(fabsf(v2.x), fabsf(v2.y)), fmaxf(fabsf(v2.z), fabsf(v2.w)));
      m = fmaxf(m, fmaxf(m0, m1));
    }
    if (u < wU) {
      float4 v = ((const float4*)w)[u];
      m = fmaxf(m, fmaxf(fmaxf(fabsf(v.x), fabsf(v.y)), fmaxf(fabsf(v.z), fabsf(v.w))));
    }
  }
#pragma unroll
  for (int off = 32; off > 0; off >>= 1) m = fmaxf(m, __shfl_xor(m, off));
  __shared__ float sm[4];
  if ((threadIdx.x & 63) == 0) sm[threadIdx.x >> 6] = m;
  __syncthreads();
  if (threadIdx.x == 0) {
    float mm = fmaxf(fmaxf(sm[0], sm[1]), fmaxf(sm[2], sm[3]));
    atomicMax((unsigned int*)(scal + which), __float_as_uint(mm));
  }
}

// ---------------- pass 2: region-split quad-cooperative quant, x2 unrolled ----------------

__device__ __forceinline__ void quant_unit(float y0, float y1, float y2, float y3,
                                           float gs, unsigned short* dst) {
  float lm = fmaxf(fmaxf(fabsf(y0), fabsf(y1)), fmaxf(fabsf(y2), fabsf(y3)));
  lm = fmaxf(lm, __shfl_xor(lm, 1));
  lm = fmaxf(lm, __shfl_xor(lm, 2));           // 16-elem block amax across the quad
  float bs = round_e4m3_f(lm / 6.0f * gs);
  float r = gs / (bs > 0.0f ? bs : 1.0f);
  ushort4 o;
  o.x = (unsigned short)(__float_as_uint(round_e2m1_f(y0 * r) * bs) >> 16);
  o.y = (unsigned short)(__float_as_uint(round_e2m1_f(y1 * r) * bs) >> 16);
  o.z = (unsigned short)(__float_as_uint(round_e2m1_f(y2 * r) * bs) >> 16);
  o.w = (unsigned short)(__float_as_uint(round_e2m1_f(y3 * r) * bs) >> 16);
  *(ushort4*)dst = o;                          // q*bs <= 6 sig bits -> exact bf16
}

__global__ void quant2_kernel(const float* __restrict__ x, const float* __restrict__ w,
                              __hip_bfloat16* __restrict__ A, __hip_bfloat16* __restrict__ B,
                              const float* __restrict__ scal, long actU, long wU,
                              int hidden, int hqLog, int AB) {
  const long hqm = (1L << hqLog) - 1;
  if ((int)blockIdx.x < AB) {
    const float gs = 2688.0f / scal[0];
    const long stride = (long)AB * blockDim.x;
    long u = (long)blockIdx.x * blockDim.x + threadIdx.x;
    for (; u + stride < actU; u += 2 * stride) {
      long ua = u, ub = u + stride;
      long ra = ua >> hqLog, ca = ua & hqm;
      long rb = ub >> hqLog, cb = ub & hqm;
      const float* xa = x + ((ra * (long)hidden) << 1) + (ca << 2);
      const float* xb = x + ((rb * (long)hidden) << 1) + (cb << 2);
      float4 a1 = *(const float4*)xa;
      float4 a2 = *(const float4*)(xa + hidden);
      float4 b1 = *(const float4*)xb;
      float4 b2 = *(const float4*)(xb + hidden);
      quant_unit(silu_mul_f(a1.x, a2.x), silu_mul_f(a1.y, a2.y),
                 silu_mul_f(a1.z, a2.z), silu_mul_f(a1.w, a2.w),
                 gs, (unsigned short*)A + (ua << 2));
      quant_unit(silu_mul_f(b1.x, b2.x), silu_mul_f(b1.y, b2.y),
                 silu_mul_f(b1.z, b2.z), silu_mul_f(b1.w, b2.w),
                 gs, (unsigned short*)A + (ub << 2));
    }
    if (u < actU) {
      long c = u & hqm;
      const float* xa = x + (((u >> hqLog) * (long)hidden) << 1) + (c << 2);
      float4 v1 = *(const float4*)xa;
      float4 v2 = *(const float4*)(xa + hidden);
      quant_unit(silu_mul_f(v1.x, v2.x), silu_mul_f(v1.y, v2.y),
                 silu_mul_f(v1.z, v2.z), silu_mul_f(v1.w, v2.w),
                 gs, (unsigned short*)A + (u << 2));
    }
  } else {
    const float gs = 2688.0f / scal[1];
    const long stride = (long)(gridDim.x - AB) * blockDim.x;
    long u = (long)((int)blockIdx.x - AB) * blockDim.x + threadIdx.x;
    for (; u + stride < wU; u += 2 * stride) {
      float4 v1 = ((const float4*)w)[u];
      float4 v2 = ((const float4*)w)[u + stride];
      quant_unit(v1.x, v1.y, v1.z, v1.w, gs, (unsigned short*)B + (u << 2));
      quant_unit(v2.x, v2.y, v2.z, v2.w, gs, (unsigned short*)B + ((u + stride) << 2));
    }
    if (u < wU) {
      float4 v = ((const float4*)w)[u];
      quant_unit(v.x, v.y, v.z, v.w, gs, (unsigned short*)B + (u << 2));
    }
  }
}

// ---------------- pass 3: 256x256 bf16 GEMM, 16x16x32 MFMA (R8-exact, measured 226us) --
// Proven geometry: 64B rows, slot swizzle phys = slot ^ ((row>>1)&3) -> 0 bank conflicts.
// Never-drain pipeline: 4 phases/tile, reads 1 phase ahead (counted lgkmcnt),
// vmcnt(4) gates at P2/P4 only. SP1 hoisted above WAITL on phases 1-3.

__device__ __forceinline__ void gload_lds16(const void* g, void* l) {
  __builtin_amdgcn_global_load_lds(
      (const __attribute__((address_space(1))) void*)(uintptr_t)g,
      (__attribute__((address_space(3))) void*)(uintptr_t)l, 16, 0, 0);
}

template <unsigned IMM>
__device__ __forceinline__ bf16x8 lds_read16o(unsigned addr) {
  bf16x8 r;
  asm volatile("ds_read_b128 %0, %1 offset:%c2" : "=&v"(r) : "v"(addr), "i"(IMM));
  return r;
}

__device__ __forceinline__ f32x4 mfma_(bf16x8 a, bf16x8 b, f32x4 c) {
  return __builtin_amdgcn_mfma_f32_16x16x32_bf16(a, b, c, 0, 0, 0);
}

#define SP1 __builtin_amdgcn_s_setprio(1)
#define SP0 __builtin_amdgcn_s_setprio(0)
#define SCHEDB __builtin_amdgcn_sched_barrier(0)
#define WAITL(n) do { asm volatile("s_waitcnt lgkmcnt(" #n ")" ::: "memory"); SCHEDB; } while (0)
#define VMW4 do { asm volatile("s_waitcnt vmcnt(4)" ::: "memory"); } while (0)

#define STAGEA(PP, HH, KSB) do {                                        \
    const char* _s = pa + (KSB) + (HH) * 64;                            \
    gload_lds16(_s, ldsStA + (PP) * 32768 + (HH) * 16384);              \
    gload_lds16(_s + rowBig, ldsStA + (PP) * 32768 + (HH) * 16384 + 8192); } while (0)

#define STAGEB(PP, HH, KSB) do {                                        \
    const char* _s = pb + (KSB) + (HH) * 64;                            \
    gload_lds16(_s, ldsStB + (PP) * 32768 + (HH) * 16384);              \
    gload_lds16(_s + rowBig, ldsStB + (PP) * 32768 + (HH) * 16384 + 8192); } while (0)

#define RDA4(DST, PP, HH, MB) do {                                              \
    DST[0] = lds_read16o<(PP)*32768u + (HH)*16384u + ((MB)+0)*1024u>(vA);       \
    DST[1] = lds_read16o<(PP)*32768u + (HH)*16384u + ((MB)+1)*1024u>(vA);       \
    DST[2] = lds_read16o<(PP)*32768u + (HH)*16384u + ((MB)+2)*1024u>(vA);       \
    DST[3] = lds_read16o<(PP)*32768u + (HH)*16384u + ((MB)+3)*1024u>(vA); } while (0)

#define RDB4(DST, PP, HH) do {                                                  \
    DST[0] = lds_read16o<(PP)*32768u + (HH)*16384u + 0u>(vB);                   \
    DST[1] = lds_read16o<(PP)*32768u + (HH)*16384u + 1024u>(vB);                \
    DST[2] = lds_read16o<(PP)*32768u + (HH)*16384u + 2048u>(vB);                \
    DST[3] = lds_read16o<(PP)*32768u + (HH)*16384u + 3072u>(vB); } while (0)

#define MFMA16(AF, BF, MB) do {                                                  \
    acc[(MB)+0][0] = mfma_(AF[0], BF[0], acc[(MB)+0][0]);                        \
    acc[(MB)+1][0] = mfma_(AF[1], BF[0], acc[(MB)+1][0]);                        \
    acc[(MB)+2][0] = mfma_(AF[2], BF[0], acc[(MB)+2][0]);                        \
    acc[(MB)+3][0] = mfma_(AF[3], BF[0], acc[(MB)+3][0]);                        \
    acc[(MB)+0][1] = mfma_(AF[0], BF[1], acc[(MB)+0][1]);                        \
    acc[(MB)+1][1] = mfma_(AF[1], BF[1], acc[(MB)+1][1]);                        \
    acc[(MB)+2][1] = mfma_(AF[2], BF[1], acc[(MB)+2][1]);                        \
    acc[(MB)+3][1] = mfma_(AF[3], BF[1], acc[(MB)+3][1]);                        \
    acc[(MB)+0][2] = mfma_(AF[0], BF[2], acc[(MB)+0][2]);                        \
    acc[(MB)+1][2] = mfma_(AF[1], BF[2], acc[(MB)+1][2]);                        \
    acc[(MB)+2][2] = mfma_(AF[2], BF[2], acc[(MB)+2][2]);                        \
    acc[(MB)+3][2] = mfma_(AF[3], BF[2], acc[(MB)+3][2]);                        \
    acc[(MB)+0][3] = mfma_(AF[0], BF[3], acc[(MB)+0][3]);                        \
    acc[(MB)+1][3] = mfma_(AF[1], BF[3], acc[(MB)+1][3]);                        \
    acc[(MB)+2][3] = mfma_(AF[2], BF[3], acc[(MB)+2][3]);                        \
    acc[(MB)+3][3] = mfma_(AF[3], BF[3], acc[(MB)+3][3]); } while (0)

#define TILE(P, KSB) do {                                                        \
    STAGEA((P)^1, 0, KSB);                                                       \
    RDA4(aY, P, 0, 4);                                                           \
    SP1; WAITL(4);                                                               \
    MFMA16(aX, bb0, 0); SP0;                                                     \
    STAGEB((P)^1, 0, KSB);                                                       \
    VMW4;                                                                        \
    __builtin_amdgcn_s_barrier(); SCHEDB;                                        \
    RDA4(aX, P, 1, 0); RDB4(bb1, P, 1);                                          \
    SP1; WAITL(8);                                                               \
    MFMA16(aY, bb0, 4); SP0;                                                     \
    STAGEA((P)^1, 1, KSB);                                                       \
    RDA4(aY, P, 1, 4);                                                           \
    SP1; WAITL(4);                                                               \
    MFMA16(aX, bb1, 0); SP0;                                                     \
    STAGEB((P)^1, 1, KSB);                                                       \
    WAITL(0);                                                                    \
    VMW4;                                                                        \
    __builtin_amdgcn_s_barrier(); SCHEDB;                                        \
    RDA4(aX, (P)^1, 0, 0); RDB4(bb0, (P)^1, 0); SCHEDB;                          \
    SP1; MFMA16(aY, bb1, 4); SP0;                                                \
  } while (0)

__global__ __launch_bounds__(512, 2) void gemm_bt_kernel(
    const __hip_bfloat16* __restrict__ A, const __hip_bfloat16* __restrict__ B,
    float* __restrict__ C, const float* __restrict__ scal, int M, int N, int K) {
  __shared__ __align__(16) char lds[131072];

  // XCD-banded wg map: each XCD gets a 4-row bm band, bn-major.
  const int nbm = M >> 8, nbn = N >> 8;
  int wg = blockIdx.x, bm, bn;
  if ((nbm & 7) == 0) {
    int band = nbm >> 3;
    int xcd = wg & 7, c = wg >> 3;
    bm = xcd * band + (c % band);
    bn = c / band;
  } else {
    bm = wg / nbn; bn = wg % nbn;
  }
  const int brow = bm << 8, bcol = bn << 8;

  const int tid = threadIdx.x;
  const int lane = tid & 63;
  const int wave = tid >> 6;
  const int wm = wave >> 2, wn = wave & 3;

  // staging: row = tid>>2, phys 16B slot = tid&3, logical kchunk = phys^((row>>1)&3)
  const int srow = tid >> 2;
  const int slc = (tid & 3) ^ ((tid >> 3) & 3);
  const char* pa = (const char*)(A + (size_t)(brow + srow) * K + slc * 8);
  const char* pb = (const char*)(B + (size_t)(bcol + srow) * K + slc * 8);
  const size_t rowBig = (size_t)128 * K * 2;
  char* ldsStA = lds + tid * 16;
  char* ldsStB = lds + 65536 + tid * 16;

  // fragment reads: row R = wbase + 16m + (lane&15); kchunk = lane>>4;
  // phys = kchunk ^ ((R>>1)&3) = kchunk ^ ((lane>>1)&3)   [measured 0 conflicts]
  const unsigned ldsBase = (unsigned)(uintptr_t)lds;
  const unsigned xoff = (unsigned)((lane & 15) * 64) +
                        ((((unsigned)(lane >> 4)) ^ (((unsigned)lane >> 1) & 3u)) << 4);
  const unsigned vA = ldsBase + (unsigned)(wm * 8192) + xoff;
  const unsigned vB = ldsBase + 65536u + (unsigned)(wn * 4096) + xoff;

  f32x4 acc[8][4] = {};
  bf16x8 aX[4], aY[4], bb0[4], bb1[4];

  // prologue: stage tile 0 fully (parity 0), publish, issue P1(tile 0) reads
  STAGEA(0, 0, 0); STAGEB(0, 0, 0); STAGEA(0, 1, 0); STAGEB(0, 1, 0);
  asm volatile("s_waitcnt vmcnt(0)" ::: "memory");
  __syncthreads();
  RDA4(aX, 0, 0, 0); RDB4(bb0, 0, 0); SCHEDB;

  const int nt = K >> 6;  // K-tiles
  for (int it = 0; it < (nt >> 1); ++it) {
    int t0 = it << 1;
    int ks0 = (t0 + 1) * 128;                       // stage tile t0+1
    int ks1 = (t0 + 2 == nt) ? 0 : (t0 + 2) * 128;  // stage tile t0+2 (dead at tail)
    TILE(0, ks0);
    TILE(1, ks1);
  }
  asm volatile("s_waitcnt lgkmcnt(0)" ::: "memory");
  asm volatile("s_waitcnt vmcnt(0)" ::: "memory");

  float gy = 2688.0f / scal[0];
  float gw = 2688.0f / scal[1];
  float alpha = 1.0f / (gy * gw);

  // C/D layout: col = lane&15, row = (lane>>4)*4 + reg
#pragma unroll
  for (int m = 0; m < 8; ++m) {
    int rbase = brow + wm * 128 + m * 16 + ((lane >> 4) << 2);
#pragma unroll
    for (int n = 0; n < 4; ++n) {
      int col = bcol + wn * 64 + n * 16 + (lane & 15);
#pragma unroll
      for (int rg = 0; rg < 4; ++rg) {
        C[(size_t)(rbase + rg) * N + col] = acc[m][n][rg] * alpha;
      }
    }
  }
}

// ---------------- launcher ----------------

extern "C" void kernel_launch(void* const* d_in, const int* in_sizes, int n_in,
                              void* d_out, int out_size, void* d_ws, size_t ws_size,
                              hipStream_t stream) {
  const float* x = (const float*)d_in[0];
  const float* w = (const float*)d_in[1];
  float* out = (float*)d_out;

  int hidden = 1;
  while ((long long)hidden * hidden < (long long)in_sizes[1]) hidden <<= 1;
  int tokens = in_sizes[0] / (2 * hidden);

  char* ws = (char*)d_ws;
  __hip_bfloat16* Aq = (__hip_bfloat16*)ws;
  __hip_bfloat16* Bq = (__hip_bfloat16*)(ws + (size_t)tokens * hidden * 2);
  float* scal = (float*)(ws + (size_t)tokens * hidden * 2 + (size_t)hidden * hidden * 2);

  long actU = (long)tokens * hidden / 4;   // float4 units of y (32 B read each)
  long wU = (long)hidden * hidden / 4;     // float4 units of w (16 B read each)
  int hqLog = __builtin_ctz((unsigned)(hidden >> 2));
  int nBlk = 2048;

  // traffic-proportional act/w block splits (R9 lesson: split by BYTES, not units)
  // amax:  act 32 B/unit, w 16 B/unit
  long abA = (long)nBlk * (actU * 2) / (actU * 2 + wU);
  // quant: act 40 B/unit (32 rd + 8 wr), w 24 B/unit (16 rd + 8 wr)
  long abQ = (long)nBlk * (actU * 5) / (actU * 5 + wU * 3);
  int AB_amax = (int)abA & ~3;
  int AB_quant = (int)abQ & ~3;
  if (AB_amax < 4) AB_amax = 4;
  if (AB_amax > nBlk - 4) AB_amax = nBlk - 4;
  if (AB_quant < 4) AB_quant = 4;
  if (AB_quant > nBlk - 4) AB_quant = nBlk - 4;

  init_scal_kernel<<<1, 64, 0, stream>>>(scal);
  amax2_kernel<<<nBlk, 256, 0, stream>>>(x, w, scal, actU, wU, hidden, hqLog, AB_amax);
  quant2_kernel<<<nBlk, 256, 0, stream>>>(x, w, Aq, Bq, scal, actU, wU, hidden, hqLog, AB_quant);

  int grid = (tokens >> 8) * (hidden >> 8);  // 256x256 tiles
  gemm_bt_kernel<<<grid, 512, 0, stream>>>(Aq, Bq, out, scal, tokens, hidden, hidden);
}